// Round 1
// baseline (360.623 us; speedup 1.0000x reference)
//
#include <hip/hip_runtime.h>
#include <math.h>

// Problem constants
#define NROWS   23328      // 8 * 54 * 54
#define CINC    64
#define COUTC   128
#define HIN     56
#define SPAT    2916       // 54*54
#define INF     576        // 64*9
#define NSLAB   18         // 576 / 32
#define SLABF   32         // features per slab
#define KSLAB   288        // 32 features * 9 channels (silu + 8 bases)
#define ASTRIDE 296        // 288 + 8 pad (2-way LDS bank aliasing = free)
#define WS_ELEMS (NSLAB * COUTC * KSLAB)   // 663552 bf16 -> 1.33 MB

typedef __bf16 bf16x8 __attribute__((ext_vector_type(8)));
typedef float  floatx4 __attribute__((ext_vector_type(4)));

// ---------------------------------------------------------------------------
// Prep: combined weight  W_s[slab][o][v*32+f]  (bf16)
//   v==0 : base_weight[o][i]           (silu channel)
//   v>=1 : spline_weight[o][i][v-1] * spline_scaler[o][i]
// where i = slab*32 + f
// ---------------------------------------------------------------------------
__global__ __launch_bounds__(256) void prep_w_kernel(
    const float* __restrict__ bw, const float* __restrict__ sw,
    const float* __restrict__ sc, __bf16* __restrict__ W)
{
    int idx = blockIdx.x * 256 + threadIdx.x;
    if (idx >= WS_ELEMS) return;
    int kl   = idx % KSLAB;
    int rest = idx / KSLAB;
    int o    = rest % COUTC;
    int slab = rest / COUTC;
    int v = kl >> 5;        // 0..8
    int f = kl & 31;
    int i = slab * SLABF + f;
    float w;
    if (v == 0) w = bw[o * INF + i];
    else        w = sw[(o * INF + i) * 8 + (v - 1)] * sc[o * INF + i];
    W[idx] = (__bf16)w;
}

// ---------------------------------------------------------------------------
// Fused KAN-conv GEMM: one block = 128 rows x 128 couts, 8 waves.
// Activations (silu + 8 uniform cubic B-spline bases) generated into LDS per
// 32-feature slab, consumed by mfma_f32_16x16x32_bf16.
// ---------------------------------------------------------------------------
__global__ __launch_bounds__(512) void kan_gemm_kernel(
    const float* __restrict__ x, const __bf16* __restrict__ W,
    float* __restrict__ out)
{
    __shared__ __align__(16) __bf16 As[128 * ASTRIDE];   // 75,776 B

    const int tid  = threadIdx.x;
    const int lane = tid & 63;
    const int wave = tid >> 6;          // 0..7
    const int quad = lane >> 4;         // 0..3
    const int l16  = lane & 15;
    const int n0   = blockIdx.x * 128;

    const int m_q = wave & 3;           // row quarter (32 rows)
    const int n_h = wave >> 2;          // col half   (64 couts)

    floatx4 acc[2][4];
#pragma unroll
    for (int a = 0; a < 2; ++a)
#pragma unroll
        for (int b = 0; b < 4; ++b) acc[a][b] = (floatx4){0.f, 0.f, 0.f, 0.f};

    // activation task: one per thread = (row_local, group of 8 features)
    const int row_local = tid >> 2;     // 0..127
    const int f8        = tid & 3;      // 0..3
    int n  = n0 + row_local;
    int nc = n < NROWS ? n : NROWS - 1; // clamp for safe gather
    int bb  = nc / SPAT;
    int rem = nc - bb * SPAT;
    int oh  = rem / 54;
    int ow  = rem - oh * 54;
    const float* xb = x + bb * (CINC * HIN * HIN);

    for (int slab = 0; slab < NSLAB; ++slab) {
        __syncthreads();   // protect previous slab's A reads
        // ---- phase A: build A-slab in LDS ----
        {
            bf16x8 vecs[9];
#pragma unroll
            for (int fl = 0; fl < 8; ++fl) {
                int i  = slab * SLABF + f8 * 8 + fl;
                int c  = i / 9;
                int rs = i - c * 9;
                int r  = rs / 3;
                int s  = rs - r * 3;
                float p = xb[(c * HIN + oh + r) * HIN + ow + s];
                // silu
                float si = p / (1.f + __expf(-p));
                // uniform cubic B-spline, grid [-2.2, 2.2], h = 0.4
                float u  = p * 2.5f + 5.5f;
                float fk = floorf(u);
                int   kk = (int)fk;
                float t  = u - fk;
                float t2 = t * t, t3 = t2 * t;
                float omt = 1.f - t;
                float w0 = omt * omt * omt * (1.f / 6.f);
                float w1 = (3.f * t3 - 6.f * t2 + 4.f) * (1.f / 6.f);
                float w2 = (-3.f * t3 + 3.f * t2 + 3.f * t + 1.f) * (1.f / 6.f);
                float w3 = t3 * (1.f / 6.f);
                bool inr = (u >= 0.f) && (u < 11.f);
                vecs[0][fl] = (__bf16)si;
#pragma unroll
                for (int g = 0; g < 8; ++g) {
                    int d = kk - g;
                    float val = (d == 3) ? w0 : (d == 2) ? w1
                              : (d == 1) ? w2 : (d == 0) ? w3 : 0.f;
                    val = inr ? val : 0.f;
                    vecs[g + 1][fl] = (__bf16)val;
                }
            }
#pragma unroll
            for (int v = 0; v < 9; ++v) {
                *(bf16x8*)(&As[row_local * ASTRIDE + v * 32 + f8 * 8]) = vecs[v];
            }
        }
        __syncthreads();
        // ---- phase B: 9 MFMA K-steps over this slab ----
        const __bf16* Wslab = W + slab * (COUTC * KSLAB);
#pragma unroll
        for (int ks = 0; ks < 9; ++ks) {
            bf16x8 bfr[4];
#pragma unroll
            for (int nt = 0; nt < 4; ++nt) {
                int o = n_h * 64 + nt * 16 + l16;
                bfr[nt] = *(const bf16x8*)(Wslab + o * KSLAB + ks * 32 + quad * 8);
            }
            bf16x8 afr[2];
#pragma unroll
            for (int mt = 0; mt < 2; ++mt) {
                int rrow = m_q * 32 + mt * 16 + l16;
                afr[mt] = *(const bf16x8*)(&As[rrow * ASTRIDE + ks * 32 + quad * 8]);
            }
#pragma unroll
            for (int mt = 0; mt < 2; ++mt)
#pragma unroll
                for (int nt = 0; nt < 4; ++nt)
                    acc[mt][nt] = __builtin_amdgcn_mfma_f32_16x16x32_bf16(
                        afr[mt], bfr[nt], acc[mt][nt], 0, 0, 0);
        }
    }

    // ---- epilogue: D row = quad*4 + reg, col = l16 (m89/m91-verified) ----
#pragma unroll
    for (int mt = 0; mt < 2; ++mt) {
#pragma unroll
        for (int r = 0; r < 4; ++r) {
            int rl = m_q * 32 + mt * 16 + quad * 4 + r;
            int nn = n0 + rl;
            if (nn < NROWS) {
                int b2   = nn / SPAT;
                int rem2 = nn - b2 * SPAT;   // oh*54 + ow
#pragma unroll
                for (int nt = 0; nt < 4; ++nt) {
                    int o = n_h * 64 + nt * 16 + l16;
                    out[(b2 * COUTC + o) * SPAT + rem2] = acc[mt][nt][r];
                }
            }
        }
    }
}

extern "C" void kernel_launch(void* const* d_in, const int* in_sizes, int n_in,
                              void* d_out, int out_size, void* d_ws, size_t ws_size,
                              hipStream_t stream) {
    const float* x  = (const float*)d_in[0];
    const float* bw = (const float*)d_in[1];
    const float* sw = (const float*)d_in[2];
    const float* sc = (const float*)d_in[3];
    float* out = (float*)d_out;
    __bf16* W  = (__bf16*)d_ws;

    prep_w_kernel<<<(WS_ELEMS + 255) / 256, 256, 0, stream>>>(bw, sw, sc, W);

    const int nblk = (NROWS + 127) / 128;   // 183
    kan_gemm_kernel<<<nblk, 512, 0, stream>>>(x, W, out);
}

// Round 2
// 205.161 us; speedup vs baseline: 1.7578x; 1.7578x over previous
//
#include <hip/hip_runtime.h>
#include <math.h>

// Problem constants
#define NROWS   23328      // 8 * 54 * 54 = 729 * 32 exactly
#define CINC    64
#define COUTC   128
#define HIN     56
#define SPAT    2916       // 54*54
#define INF     576        // 64*9
#define NSLAB   18         // 576 / 32
#define SLABF   32         // features per slab
#define KSLAB   288        // 32 features * 9 channels (silu + 8 bases)
#define ASTRIDE 296        // 288 + 8 pad
#define ROWS_B  32         // rows per block
#define NBLK    729
#define WS_ELEMS (NSLAB * COUTC * KSLAB)   // 663552 bf16 -> 1.33 MB

typedef __bf16 bf16x8 __attribute__((ext_vector_type(8)));
typedef __bf16 bf16x4 __attribute__((ext_vector_type(4)));
typedef float  floatx4 __attribute__((ext_vector_type(4)));

// ---------------------------------------------------------------------------
// Prep: combined weight  W_s[slab][o][v*32+f]  (bf16)
// ---------------------------------------------------------------------------
__global__ __launch_bounds__(256) void prep_w_kernel(
    const float* __restrict__ bw, const float* __restrict__ sw,
    const float* __restrict__ sc, __bf16* __restrict__ W)
{
    int idx = blockIdx.x * 256 + threadIdx.x;
    if (idx >= WS_ELEMS) return;
    int kl   = idx % KSLAB;
    int rest = idx / KSLAB;
    int o    = rest % COUTC;
    int slab = rest / COUTC;
    int v = kl >> 5;        // 0..8
    int f = kl & 31;
    int i = slab * SLABF + f;
    float w;
    if (v == 0) w = bw[o * INF + i];
    else        w = sw[(o * INF + i) * 8 + (v - 1)] * sc[o * INF + i];
    W[idx] = (__bf16)w;
}

// ---------------------------------------------------------------------------
// Fused KAN-conv GEMM: 729 blocks of 32 rows x 128 couts, 4 waves.
// Double-buffered A-slab in LDS; one barrier per slab; x-loads for slab s+1
// issued before MFMA(s) to hide latency; W as MFMA A-operand so that D's
// col index = row index -> coalesced epilogue stores.
// ---------------------------------------------------------------------------
__global__ __launch_bounds__(256, 4) void kan_gemm_kernel(
    const float* __restrict__ x, const __bf16* __restrict__ W,
    float* __restrict__ out)
{
    __shared__ __align__(16) __bf16 As[2][ROWS_B * ASTRIDE];   // 37,888 B

    const int tid  = threadIdx.x;
    const int lane = tid & 63;
    const int wave = tid >> 6;          // 0..3 -> cout group of 32
    const int quad = lane >> 4;         // 0..3
    const int l16  = lane & 15;
    const int n0   = blockIdx.x * ROWS_B;

    floatx4 acc[2][2];                  // [row-tile][cout-tile]
#pragma unroll
    for (int a = 0; a < 2; ++a)
#pragma unroll
        for (int b = 0; b < 2; ++b) acc[a][b] = (floatx4){0.f, 0.f, 0.f, 0.f};

    // activation task: thread -> (row_local, group of 4 features per slab)
    const int row_local = tid >> 3;     // 0..31
    const int f4        = tid & 7;      // 0..7
    const int n   = n0 + row_local;
    const int bb  = n / SPAT;
    const int rem = n - bb * SPAT;
    const int oh  = rem / 54;
    const int ow  = rem - oh * 54;
    const float* xb = x + bb * (CINC * HIN * HIN) + (oh * HIN + ow);

    // ---- activation math: 4 features of `slab` -> 9 bf16x4 vectors ----
    auto act_math = [&](const float* pv, bf16x4* vecs) {
#pragma unroll
        for (int fl = 0; fl < 4; ++fl) {
            float p  = pv[fl];
            float si = p / (1.f + __expf(-p));          // silu
            float u  = p * 2.5f + 5.5f;                 // uniform cubic B-spline
            float fk = floorf(u);
            int   kk = (int)fk;
            float t  = u - fk;
            float t2 = t * t, t3 = t2 * t;
            float omt = 1.f - t;
            float w0 = omt * omt * omt * (1.f / 6.f);
            float w1 = (3.f * t3 - 6.f * t2 + 4.f) * (1.f / 6.f);
            float w2 = (-3.f * t3 + 3.f * t2 + 3.f * t + 1.f) * (1.f / 6.f);
            float w3 = t3 * (1.f / 6.f);
            bool inr = (u >= 0.f) && (u < 11.f);
            vecs[0][fl] = (__bf16)si;
#pragma unroll
            for (int g = 0; g < 8; ++g) {
                int d = kk - g;
                float val = (d == 3) ? w0 : (d == 2) ? w1
                          : (d == 1) ? w2 : (d == 0) ? w3 : 0.f;
                vecs[g + 1][fl] = (__bf16)(inr ? val : 0.f);
            }
        }
    };
    auto act_load = [&](int slab, float* pv) {
#pragma unroll
        for (int fl = 0; fl < 4; ++fl) {
            int i  = slab * SLABF + f4 * 4 + fl;
            int c  = i / 9;
            int rs = i - c * 9;
            int r  = rs / 3;
            int s  = rs - r * 3;
            pv[fl] = xb[c * (HIN * HIN) + r * HIN + s];
        }
    };
    auto act_store = [&](int buf, bf16x4* vecs) {
#pragma unroll
        for (int v = 0; v < 9; ++v)
            *(bf16x4*)(&As[buf][row_local * ASTRIDE + v * 32 + f4 * 4]) = vecs[v];
    };

    // ---- prologue: build slab 0 ----
    {
        float pv[4]; bf16x4 vecs[9];
        act_load(0, pv);
        act_math(pv, vecs);
        act_store(0, vecs);
    }
    __syncthreads();

    for (int slab = 0; slab < NSLAB; ++slab) {
        const int buf = slab & 1;
        const bool have_next = (slab + 1 < NSLAB);
        float pv[4];
        if (have_next) act_load(slab + 1, pv);   // in flight during MFMA(s)

        // ---- MFMA over slab: 9 K-steps ----
        const __bf16* Wslab = W + slab * (COUTC * KSLAB);
#pragma unroll
        for (int ks = 0; ks < 9; ++ks) {
            bf16x8 wfr[2];                       // A operand: couts
#pragma unroll
            for (int nt = 0; nt < 2; ++nt) {
                int o = wave * 32 + nt * 16 + l16;
                wfr[nt] = *(const bf16x8*)(Wslab + o * KSLAB + ks * 32 + quad * 8);
            }
            bf16x8 afr[2];                       // B operand: rows from LDS
#pragma unroll
            for (int mt = 0; mt < 2; ++mt) {
                int rr = mt * 16 + l16;
                afr[mt] = *(const bf16x8*)(&As[buf][rr * ASTRIDE + ks * 32 + quad * 8]);
            }
#pragma unroll
            for (int mt = 0; mt < 2; ++mt)
#pragma unroll
                for (int nt = 0; nt < 2; ++nt)
                    acc[mt][nt] = __builtin_amdgcn_mfma_f32_16x16x32_bf16(
                        wfr[nt], afr[mt], acc[mt][nt], 0, 0, 0);
        }

        if (have_next) {
            bf16x4 vecs[9];
            act_math(pv, vecs);
            act_store(buf ^ 1, vecs);
        }
        __syncthreads();
    }

    // ---- epilogue: D col(l16) = row index, row(quad*4+r) = cout ----
#pragma unroll
    for (int mt = 0; mt < 2; ++mt) {
        int nn   = n0 + mt * 16 + l16;
        int b2   = nn / SPAT;
        int rem2 = nn - b2 * SPAT;
#pragma unroll
        for (int nt = 0; nt < 2; ++nt) {
#pragma unroll
            for (int r = 0; r < 4; ++r) {
                int o = wave * 32 + nt * 16 + quad * 4 + r;
                out[(b2 * COUTC + o) * SPAT + rem2] = acc[mt][nt][r];
            }
        }
    }
}

extern "C" void kernel_launch(void* const* d_in, const int* in_sizes, int n_in,
                              void* d_out, int out_size, void* d_ws, size_t ws_size,
                              hipStream_t stream) {
    const float* x  = (const float*)d_in[0];
    const float* bw = (const float*)d_in[1];
    const float* sw = (const float*)d_in[2];
    const float* sc = (const float*)d_in[3];
    float* out = (float*)d_out;
    __bf16* W  = (__bf16*)d_ws;

    prep_w_kernel<<<(WS_ELEMS + 255) / 256, 256, 0, stream>>>(bw, sw, sc, W);
    kan_gemm_kernel<<<NBLK, 256, 0, stream>>>(x, W, out);
}

// Round 3
// 179.602 us; speedup vs baseline: 2.0079x; 1.1423x over previous
//
#include <hip/hip_runtime.h>
#include <math.h>

// ---------------- problem constants ----------------
#define NROWS  23328           // 8 * 54 * 54 = 243 * 96
#define SPAT   2916            // 54*54
#define HIN    56
#define IMG    3136            // 56*56
#define CIMG   200704          // 64*3136 (per-batch x stride)
#define NPIX   1605632         // 8*64*3136
#define NHW    25088           // 8*3136
#define KS_SP  144             // spline k-steps (576 feat * 8ch / 32)
#define KS_B   18              // base  k-steps (576 / 32)

// ---------------- ws layout (bytes) ----------------
#define WSP_OFF   0u                         // [144][128][32] bf16 = 1179648
#define WB_OFF    1179648u                   // [18][128][32]  bf16 = 147456
#define TAB_OFF   1327104u                   // [162][4] int32 = 2592
#define ACT8_OFF  1335296u                   // [NPIX][8] bf16 = 25690112
#define SILU_OFF  27025408u                  // [NHW][64] bf16 = 3211264
// total: 30,236,672 bytes

// prep-kernel idx ranges (silu first: heaviest per-thread work dispatches early)
#define R_SIL_END  25088
#define R_WSP_END  614912                    // +589824
#define R_WB_END   688640                    // +73728
#define R_TAB_END  689288                    // +648
#define R_ACT_END  2294920                   // +1605632

typedef __bf16 bf16x8 __attribute__((ext_vector_type(8)));
typedef float  floatx4 __attribute__((ext_vector_type(4)));

__device__ __forceinline__ float silu_f(float p) {
    return p / (1.f + __expf(-p));
}

// spline bases for one value -> 8 bf16 channels
__device__ __forceinline__ bf16x8 bases8(float p) {
    float u  = p * 2.5f + 5.5f;              // uniform grid [-2.2,2.2], h=0.4
    float fk = floorf(u);
    int   kk = (int)fk;
    float t  = u - fk;
    float t2 = t * t, t3 = t2 * t;
    float omt = 1.f - t;
    float w0 = omt * omt * omt * (1.f / 6.f);
    float w1 = (3.f * t3 - 6.f * t2 + 4.f) * (1.f / 6.f);
    float w2 = (-3.f * t3 + 3.f * t2 + 3.f * t + 1.f) * (1.f / 6.f);
    float w3 = t3 * (1.f / 6.f);
    bool inr = (u >= 0.f) && (u < 11.f);
    bf16x8 v;
#pragma unroll
    for (int g = 0; g < 8; ++g) {
        int d = kk - g;
        float val = (d == 3) ? w0 : (d == 2) ? w1
                  : (d == 1) ? w2 : (d == 0) ? w3 : 0.f;
        v[g] = (__bf16)(inr ? val : 0.f);
    }
    return v;
}

// ---------------------------------------------------------------------------
// Fused prep: silu_t transpose, Wsp, Wb, offset table, act8 planes.
// ---------------------------------------------------------------------------
__global__ __launch_bounds__(256) void prep_kernel(
    const float* __restrict__ x, const float* __restrict__ bw,
    const float* __restrict__ sw, const float* __restrict__ sc,
    char* __restrict__ ws)
{
    __bf16* Wsp   = (__bf16*)(ws + WSP_OFF);
    __bf16* Wb    = (__bf16*)(ws + WB_OFF);
    int*    tab   = (int*)   (ws + TAB_OFF);
    __bf16* act8  = (__bf16*)(ws + ACT8_OFF);
    __bf16* silu_t= (__bf16*)(ws + SILU_OFF);

    int idx = blockIdx.x * 256 + threadIdx.x;
    if (idx < R_SIL_END) {
        // silu_t[b][hw][c] from x[b][c][hw]
        int b  = idx / IMG;
        int hw = idx - b * IMG;
        const float* xb = x + b * CIMG + hw;
        __bf16* dst = silu_t + (size_t)idx * 64;
#pragma unroll
        for (int c8 = 0; c8 < 8; ++c8) {
            bf16x8 v;
#pragma unroll
            for (int j = 0; j < 8; ++j) {
                float p = xb[(c8 * 8 + j) * IMG];
                v[j] = (__bf16)silu_f(p);
            }
            *(bf16x8*)(dst + c8 * 8) = v;
        }
    } else if (idx < R_WSP_END) {
        int iw = idx - R_SIL_END;
        int kl = iw & 31;                    // q*8+j
        int o  = (iw >> 5) & 127;
        int ks = iw >> 12;
        int f  = ks * 4 + (kl >> 3);
        int j  = kl & 7;
        Wsp[iw] = (__bf16)(sw[(o * 576 + f) * 8 + j] * sc[o * 576 + f]);
    } else if (idx < R_WB_END) {
        int ib = idx - R_WSP_END;
        int kl = ib & 31;
        int o  = (ib >> 5) & 127;
        int kb = ib >> 12;
        int c  = (kb & 1) * 32 + kl;
        int rs = kb >> 1;
        Wb[ib] = (__bf16)bw[o * 576 + c * 9 + rs];
    } else if (idx < R_TAB_END) {
        int e  = idx - R_WB_END;
        int ks = e >> 2, q = e & 3;
        int off;
        if (ks < KS_SP) {                    // pixel offset into act8 plane
            int f  = ks * 4 + q;
            int c  = f / 9;
            int rs = f - c * 9;
            off = c * IMG + (rs / 3) * HIN + (rs % 3);
        } else {                             // elem offset into silu_t
            int kb = ks - KS_SP;
            int rs = kb >> 1;
            off = ((rs / 3) * HIN + (rs % 3)) * 64 + (kb & 1) * 32 + q * 8;
        }
        tab[e] = off;
    } else if (idx < R_ACT_END) {
        int i = idx - R_TAB_END;             // pixel index
        float p = x[i];
        *(bf16x8*)(act8 + (size_t)i * 8) = bases8(p);
    }
}

// ---------------------------------------------------------------------------
// Streaming GEMM: 243 blocks x 768 threads (12 waves), block = 96 rows x 128
// couts, wave = 32 rows x 32 couts (2x2 16x16 tiles). No LDS, no barriers:
// A-fragments are direct 16B global loads from precomputed act8 / silu_t.
// mfma(W-frag, A-frag, acc): D row = cout(quad*4+r), col = n(l16) -> coalesced.
// ---------------------------------------------------------------------------
__global__ __launch_bounds__(768, 3) void kan_gemm(
    const char* __restrict__ ws, float* __restrict__ out)
{
    const __bf16* Wsp    = (const __bf16*)(ws + WSP_OFF);
    const __bf16* Wb     = (const __bf16*)(ws + WB_OFF);
    const int*    tab    = (const int*)   (ws + TAB_OFF);
    const __bf16* act8   = (const __bf16*)(ws + ACT8_OFF);
    const __bf16* silu_t = (const __bf16*)(ws + SILU_OFF);

    const int tid   = threadIdx.x;
    const int lane  = tid & 63;
    const int wave  = tid >> 6;          // 0..11
    const int quad  = lane >> 4;
    const int l16   = lane & 15;
    const int coutg = wave & 3;          // 4 cout groups of 32
    const int rowg  = wave >> 2;         // 3 row groups of 32
    const int n0    = blockIdx.x * 96 + rowg * 32;

    int pixbase[2], silbase[2], bidx[2], rem[2];
#pragma unroll
    for (int mt = 0; mt < 2; ++mt) {
        int n  = n0 + mt * 16 + l16;
        int b  = n / SPAT;
        int r  = n - b * SPAT;
        int oh = r / 54, ow = r - oh * 54;
        bidx[mt] = b; rem[mt] = r;
        pixbase[mt] = b * CIMG + oh * HIN + ow;
        silbase[mt] = (b * IMG + oh * HIN + ow) * 64;
    }

    floatx4 acc[2][2] = {};
    const int wofs = (coutg * 32 + l16) * 32 + quad * 8;

    // ---- spline part: 144 k-steps ----
#pragma unroll 4
    for (int ks = 0; ks < KS_SP; ++ks) {
        int off = tab[4 * ks + quad];
        bf16x8 wfr[2], afr[2];
#pragma unroll
        for (int nt = 0; nt < 2; ++nt)
            wfr[nt] = *(const bf16x8*)(Wsp + ks * 4096 + nt * 512 + wofs);
#pragma unroll
        for (int mt = 0; mt < 2; ++mt)
            afr[mt] = *(const bf16x8*)(act8 + (size_t)(pixbase[mt] + off) * 8);
#pragma unroll
        for (int mt = 0; mt < 2; ++mt)
#pragma unroll
            for (int nt = 0; nt < 2; ++nt)
                acc[mt][nt] = __builtin_amdgcn_mfma_f32_16x16x32_bf16(
                    wfr[nt], afr[mt], acc[mt][nt], 0, 0, 0);
    }

    // ---- base (silu) part: 18 k-steps, K-order (r,s)-major, c-last ----
#pragma unroll 2
    for (int kb = 0; kb < KS_B; ++kb) {
        int off = tab[4 * (KS_SP + kb) + quad];
        bf16x8 wfr[2], afr[2];
#pragma unroll
        for (int nt = 0; nt < 2; ++nt)
            wfr[nt] = *(const bf16x8*)(Wb + kb * 4096 + nt * 512 + wofs);
#pragma unroll
        for (int mt = 0; mt < 2; ++mt)
            afr[mt] = *(const bf16x8*)(silu_t + silbase[mt] + off);
#pragma unroll
        for (int mt = 0; mt < 2; ++mt)
#pragma unroll
            for (int nt = 0; nt < 2; ++nt)
                acc[mt][nt] = __builtin_amdgcn_mfma_f32_16x16x32_bf16(
                    wfr[nt], afr[mt], acc[mt][nt], 0, 0, 0);
    }

    // ---- epilogue: D col(l16) = row n, D row(quad*4+r) = cout ----
#pragma unroll
    for (int mt = 0; mt < 2; ++mt) {
#pragma unroll
        for (int nt = 0; nt < 2; ++nt) {
#pragma unroll
            for (int r = 0; r < 4; ++r) {
                int o = coutg * 32 + nt * 16 + quad * 4 + r;
                out[(size_t)(bidx[mt] * 128 + o) * SPAT + rem[mt]] = acc[mt][nt][r];
            }
        }
    }
}

extern "C" void kernel_launch(void* const* d_in, const int* in_sizes, int n_in,
                              void* d_out, int out_size, void* d_ws, size_t ws_size,
                              hipStream_t stream) {
    const float* x  = (const float*)d_in[0];
    const float* bw = (const float*)d_in[1];
    const float* sw = (const float*)d_in[2];
    const float* sc = (const float*)d_in[3];
    float* out = (float*)d_out;
    char*  ws  = (char*)d_ws;

    prep_kernel<<<(R_ACT_END + 255) / 256, 256, 0, stream>>>(x, bw, sw, sc, ws);
    kan_gemm<<<243, 768, 0, stream>>>(ws, out);
}

// Round 4
// 171.603 us; speedup vs baseline: 2.1015x; 1.0466x over previous
//
#include <hip/hip_runtime.h>
#include <math.h>

// ---------------- problem constants ----------------
#define NROWS  23328           // 8 * 54 * 54
#define SPAT   2916            // 54*54
#define HIN    56
#define IMG    3136            // 56*56
#define CIMG   200704          // 64*3136 (per-batch x stride)
#define NPIX   1605632         // 8*64*3136
#define NHW    25088           // 8*3136
#define KS_ALL 162             // 144 spline + 18 base k-steps
#define CH     9               // k-steps per LDS chunk
#define NCHUNK 18

// ---------------- ws layout (bytes) ----------------
#define WSP_OFF   0u                         // [162][128][32] bf16 (spline 144 + base 18)
#define TAB_OFF   1327104u                   // (unused, kept for layout stability)
#define ACT8_OFF  1335296u                   // [NPIX][8] bf16 = 25690112
#define SILU_OFF  27025408u                  // [NHW][64] bf16 = 3211264
// total: 30,236,672 bytes

// prep idx ranges
#define R_SIL_END  200704                    // NHW*8 threads, 16B stores
#define R_WSP_END  790528                    // +589824
#define R_WB_END   864256                    // +73728
#define R_ACT_END  1265664                   // +401408 (NPIX/4 threads)

typedef __bf16 bf16x8 __attribute__((ext_vector_type(8)));
typedef float  floatx4 __attribute__((ext_vector_type(4)));

__device__ __forceinline__ float silu_f(float p) {
    return p / (1.f + __expf(-p));
}

__device__ __forceinline__ bf16x8 bases8(float p) {
    float u  = p * 2.5f + 5.5f;              // uniform grid [-2.2,2.2], h=0.4
    float fk = floorf(u);
    int   kk = (int)fk;
    float t  = u - fk;
    float t2 = t * t, t3 = t2 * t;
    float omt = 1.f - t;
    float w0 = omt * omt * omt * (1.f / 6.f);
    float w1 = (3.f * t3 - 6.f * t2 + 4.f) * (1.f / 6.f);
    float w2 = (-3.f * t3 + 3.f * t2 + 3.f * t + 1.f) * (1.f / 6.f);
    float w3 = t3 * (1.f / 6.f);
    bool inr = (u >= 0.f) && (u < 11.f);
    bf16x8 v;
#pragma unroll
    for (int g = 0; g < 8; ++g) {
        int d = kk - g;
        float val = (d == 3) ? w0 : (d == 2) ? w1
                  : (d == 1) ? w2 : (d == 0) ? w3 : 0.f;
        v[g] = (__bf16)(inr ? val : 0.f);
    }
    return v;
}

// ---------------------------------------------------------------------------
// Prep: silu transpose (16B c-contiguous stores), W planes, act8 (float4 in,
// 64B out).
// ---------------------------------------------------------------------------
__global__ __launch_bounds__(256) void prep_kernel(
    const float* __restrict__ x, const float* __restrict__ bw,
    const float* __restrict__ sw, const float* __restrict__ sc,
    char* __restrict__ ws)
{
    __bf16* W     = (__bf16*)(ws + WSP_OFF);
    __bf16* act8  = (__bf16*)(ws + ACT8_OFF);
    __bf16* silu_t= (__bf16*)(ws + SILU_OFF);

    int idx = blockIdx.x * 256 + threadIdx.x;
    if (idx < R_SIL_END) {
        // one 16B store: silu_t[b][hw][c8*8 .. +8]
        int c8 = idx & 7;
        int r  = idx >> 3;                   // b*IMG + hw
        int b  = r / IMG;
        int hw = r - b * IMG;
        const float* xb = x + b * CIMG + (c8 * 8) * IMG + hw;
        bf16x8 v;
#pragma unroll
        for (int j = 0; j < 8; ++j) v[j] = (__bf16)silu_f(xb[j * IMG]);
        *(bf16x8*)(silu_t + (size_t)r * 64 + c8 * 8) = v;
    } else if (idx < R_WSP_END) {
        int iw = idx - R_SIL_END;
        int kl = iw & 31;                    // q*8+j
        int o  = (iw >> 5) & 127;
        int ks = iw >> 12;
        int f  = ks * 4 + (kl >> 3);
        int j  = kl & 7;
        W[iw] = (__bf16)(sw[(o * 576 + f) * 8 + j] * sc[o * 576 + f]);
    } else if (idx < R_WB_END) {
        int ib = idx - R_WSP_END;
        int kl = ib & 31;
        int o  = (ib >> 5) & 127;
        int kb = ib >> 12;
        int c  = (kb & 1) * 32 + kl;
        int rs = kb >> 1;
        W[144 * 4096 + ib] = (__bf16)bw[o * 576 + c * 9 + rs];
    } else if (idx < R_ACT_END) {
        int i4 = idx - R_WB_END;             // 4 pixels per thread
        float4 p = ((const float4*)x)[i4];
        __bf16* dst = act8 + (size_t)i4 * 32;
        *(bf16x8*)(dst)      = bases8(p.x);
        *(bf16x8*)(dst + 8)  = bases8(p.y);
        *(bf16x8*)(dst + 16) = bases8(p.z);
        *(bf16x8*)(dst + 24) = bases8(p.w);
    }
}

// ---------------------------------------------------------------------------
// GEMM: 365 blocks x 512 threads (8 waves), block = 64 rows x 128 couts,
// wave = 32 rows x 32 couts. A-fragments staged into double-buffered LDS in
// chunks of 9 k-steps (loads issued before the MFMAs of the current chunk);
// W streams from L2. One barrier per chunk.
// ---------------------------------------------------------------------------
__global__ __launch_bounds__(512, 4) void kan_gemm(
    const char* __restrict__ ws, float* __restrict__ out)
{
    const __bf16* W      = (const __bf16*)(ws + WSP_OFF);
    const __bf16* act8   = (const __bf16*)(ws + ACT8_OFF);
    const __bf16* silu_t = (const __bf16*)(ws + SILU_OFF);

    __shared__ __align__(16) bf16x8 As[2][CH * 4 * 64];   // 73,728 B

    const int tid   = threadIdx.x;
    const int lane  = tid & 63;
    const int wave  = tid >> 6;          // 0..7
    const int quad  = lane >> 4;
    const int l16   = lane & 15;
    const int coutg = wave & 3;
    const int rowg  = wave >> 2;         // 0..1
    const int n0    = blockIdx.x * 64;

    // staging identity: row = lane, e-group = wave
    const int nrow = n0 + lane;
    const int ncl  = nrow < NROWS ? nrow : NROWS - 1;
    const int bb   = ncl / SPAT;
    const int rr   = ncl - bb * SPAT;
    const int ohh  = rr / 54, oww = rr - ohh * 54;
    const size_t pixbase = (size_t)bb * CIMG + ohh * HIN + oww;   // pixel idx
    const size_t silbase = ((size_t)bb * IMG + ohh * HIN + oww) * 64;

    floatx4 acc[2][2] = {};
    const int wofs = (coutg * 32 + l16) * 32 + quad * 8;

    auto issue_loads = [&](int ch, bf16x8* st) {
#pragma unroll
        for (int j = 0; j < 5; ++j) {
            int e = wave + 8 * j;
            if (e < 36) {
                int ksg = ch * CH + (e >> 2);
                int q   = e & 3;
                const __bf16* src;
                if (ksg < 144) {
                    int f  = ksg * 4 + q;        // feature 0..575
                    int c  = f / 9;
                    int rs = f - c * 9;
                    int off = c * IMG + (rs / 3) * HIN + (rs - (rs / 3) * 3);
                    src = act8 + (pixbase + off) * 8;
                } else {
                    int kb = ksg - 144;
                    int rs = kb >> 1;
                    int off = ((rs / 3) * HIN + (rs - (rs / 3) * 3)) * 64
                            + (kb & 1) * 32 + q * 8;
                    src = silu_t + silbase + off;
                }
                st[j] = *(const bf16x8*)src;
            }
        }
    };
    auto write_lds = [&](int buf, bf16x8* st) {
#pragma unroll
        for (int j = 0; j < 5; ++j) {
            int e = wave + 8 * j;
            if (e < 36) As[buf][e * 64 + lane] = st[j];
        }
    };

    {
        bf16x8 st[5];
        issue_loads(0, st);
        write_lds(0, st);
    }
    __syncthreads();

    for (int ch = 0; ch < NCHUNK; ++ch) {
        const int buf = ch & 1;
        bf16x8 nx[5];
        if (ch + 1 < NCHUNK) issue_loads(ch + 1, nx);   // in flight during MFMA

        const __bf16* Wc = W + (size_t)ch * (CH * 4096);
#pragma unroll
        for (int ks = 0; ks < CH; ++ks) {
            bf16x8 wfr[2], afr[2];
#pragma unroll
            for (int nt = 0; nt < 2; ++nt)
                wfr[nt] = *(const bf16x8*)(Wc + ks * 4096 + nt * 512 + wofs);
#pragma unroll
            for (int mt = 0; mt < 2; ++mt)
                afr[mt] = As[buf][(ks * 4 + quad) * 64 + rowg * 32 + mt * 16 + l16];
#pragma unroll
            for (int mt = 0; mt < 2; ++mt)
#pragma unroll
                for (int nt = 0; nt < 2; ++nt)
                    acc[mt][nt] = __builtin_amdgcn_mfma_f32_16x16x32_bf16(
                        wfr[nt], afr[mt], acc[mt][nt], 0, 0, 0);
        }

        if (ch + 1 < NCHUNK) write_lds(buf ^ 1, nx);
        __syncthreads();
    }

    // epilogue: D col(l16) = row n, D row(quad*4+r) = cout -> coalesced stores
#pragma unroll
    for (int mt = 0; mt < 2; ++mt) {
        int nn = n0 + rowg * 32 + mt * 16 + l16;
        if (nn < NROWS) {
            int b2   = nn / SPAT;
            int rem2 = nn - b2 * SPAT;
#pragma unroll
            for (int nt = 0; nt < 2; ++nt) {
#pragma unroll
                for (int r = 0; r < 4; ++r) {
                    int o = coutg * 32 + nt * 16 + quad * 4 + r;
                    out[(size_t)(b2 * 128 + o) * SPAT + rem2] = acc[mt][nt][r];
                }
            }
        }
    }
}

extern "C" void kernel_launch(void* const* d_in, const int* in_sizes, int n_in,
                              void* d_out, int out_size, void* d_ws, size_t ws_size,
                              hipStream_t stream) {
    const float* x  = (const float*)d_in[0];
    const float* bw = (const float*)d_in[1];
    const float* sw = (const float*)d_in[2];
    const float* sc = (const float*)d_in[3];
    float* out = (float*)d_out;
    char*  ws  = (char*)d_ws;

    prep_kernel<<<(R_ACT_END + 255) / 256, 256, 0, stream>>>(x, bw, sw, sc, ws);
    kan_gemm<<<(NROWS + 63) / 64, 512, 0, stream>>>(ws, out);
}

// Round 5
// 142.590 us; speedup vs baseline: 2.5291x; 1.2035x over previous
//
#include <hip/hip_runtime.h>
#include <math.h>

// ---------------- problem constants ----------------
#define NROWS  23328           // 8 * 54 * 54 = 243 * 96
#define SPAT   2916            // 54*54
#define HIN    56
#define IMG    3136            // 56*56
#define CIMG   200704          // 64*3136
#define NOUT   2985984         // 23328*128
#define NCH    27              // chunks per K-half (81 K32-steps / 3)

// ---------------- ws layout (bytes) ----------------
#define W2_OFF    0u                         // [648][128][8] bf16 = 1327104
#define ACT8_OFF  1335296u                   // [NPIX][8] bf16 = 25690112
#define SILU_OFF  27025408u                  // [NHW][64] bf16 = 3211264
#define PART_OFF  30236672u                  // [2][NOUT] f32 = 23887872
#define WS_NEED   (PART_OFF + 2u * NOUT * 4u)

// prep idx ranges
#define R_SIL_END  200704
#define R_W2_END   864256                    // +663552
#define R_ACT_END  1265664                   // +401408

typedef __bf16 bf16x8 __attribute__((ext_vector_type(8)));
typedef float  floatx4 __attribute__((ext_vector_type(4)));

#define GL2LDS(SRC, DST) __builtin_amdgcn_global_load_lds( \
    (const __attribute__((address_space(1))) unsigned int*)(SRC), \
    (__attribute__((address_space(3))) unsigned int*)(DST), 16, 0, 0)

__device__ __forceinline__ float silu_f(float p) {
    return p / (1.f + __expf(-p));
}

__device__ __forceinline__ bf16x8 bases8(float p) {
    float u  = p * 2.5f + 5.5f;              // uniform grid [-2.2,2.2], h=0.4
    float fk = floorf(u);
    int   kk = (int)fk;
    float t  = u - fk;
    float t2 = t * t, t3 = t2 * t;
    float omt = 1.f - t;
    float w0 = omt * omt * omt * (1.f / 6.f);
    float w1 = (3.f * t3 - 6.f * t2 + 4.f) * (1.f / 6.f);
    float w2 = (-3.f * t3 + 3.f * t2 + 3.f * t + 1.f) * (1.f / 6.f);
    float w3 = t3 * (1.f / 6.f);
    bool inr = (u >= 0.f) && (u < 11.f);
    bf16x8 v;
#pragma unroll
    for (int g = 0; g < 8; ++g) {
        int d = kk - g;
        float val = (d == 3) ? w0 : (d == 2) ? w1
                  : (d == 1) ? w2 : (d == 0) ? w3 : 0.f;
        v[g] = (__bf16)(inr ? val : 0.f);
    }
    return v;
}

// ---------------------------------------------------------------------------
// Prep: silu transpose, W2 planes ([g][cout][8], g = k/8), act8 planes.
// K order: k<4608 spline (f = k/8, ch j = k%8); k>=4608 base, kb = rs*64+c.
// ---------------------------------------------------------------------------
__global__ __launch_bounds__(256) void prep_kernel(
    const float* __restrict__ x, const float* __restrict__ bw,
    const float* __restrict__ sw, const float* __restrict__ sc,
    char* __restrict__ ws)
{
    __bf16* W2    = (__bf16*)(ws + W2_OFF);
    __bf16* act8  = (__bf16*)(ws + ACT8_OFF);
    __bf16* silu_t= (__bf16*)(ws + SILU_OFF);

    int idx = blockIdx.x * 256 + threadIdx.x;
    if (idx < R_SIL_END) {
        int c8 = idx & 7;
        int r  = idx >> 3;                   // b*IMG + hw
        int b  = r / IMG;
        int hw = r - b * IMG;
        const float* xb = x + b * CIMG + (c8 * 8) * IMG + hw;
        bf16x8 v;
#pragma unroll
        for (int j = 0; j < 8; ++j) v[j] = (__bf16)silu_f(xb[j * IMG]);
        *(bf16x8*)(silu_t + (size_t)r * 64 + c8 * 8) = v;
    } else if (idx < R_W2_END) {
        int iw = idx - R_SIL_END;
        int j  = iw & 7;
        int o  = (iw >> 3) & 127;
        int g  = iw >> 10;                   // 0..647
        float val;
        if (g < 576) {
            val = sw[(o * 576 + g) * 8 + j] * sc[o * 576 + g];
        } else {
            int eb = g - 576;
            int rs = eb >> 3;
            int c  = (eb & 7) * 8 + j;
            val = bw[o * 576 + c * 9 + rs];
        }
        W2[iw] = (__bf16)val;
    } else if (idx < R_ACT_END) {
        int i4 = idx - R_W2_END;
        float4 p = ((const float4*)x)[i4];
        __bf16* dst = act8 + (size_t)i4 * 32;
        *(bf16x8*)(dst)      = bases8(p.x);
        *(bf16x8*)(dst + 8)  = bases8(p.y);
        *(bf16x8*)(dst + 16) = bases8(p.z);
        *(bf16x8*)(dst + 24) = bases8(p.w);
    }
}

// ---------------------------------------------------------------------------
// GEMM: 486 blocks (243 row-blocks x 2 K-halves) x 768 threads (12 waves).
// Block = 96 rows x 128 couts x half-K. A staged by async global_load_lds,
// double-buffered, 3 K-steps/chunk, one barrier per chunk. MODE 0: write fp32
// partials to ws; MODE 1: atomicAdd into pre-zeroed out.
// ---------------------------------------------------------------------------
template <int MODE>
__global__ __launch_bounds__(768, 4) void kan_gemm(
    char* __restrict__ ws, float* __restrict__ outp)
{
    const __bf16* W2     = (const __bf16*)(ws + W2_OFF);
    const __bf16* act8   = (const __bf16*)(ws + ACT8_OFF);
    const __bf16* silu_t = (const __bf16*)(ws + SILU_OFF);
    float*        part   = (float*)(ws + PART_OFF);

    __shared__ __align__(16) char As[2][12 * 96 * 16];   // 36,864 B

    const int tid   = threadIdx.x;
    const int lane  = tid & 63;
    const int wave  = tid >> 6;          // 0..11
    const int quad  = lane >> 4;
    const int l16   = lane & 15;
    const int coutg = wave & 3;
    const int rowg  = wave >> 2;         // 0..2
    const int half  = blockIdx.x & 1;
    const int n0    = (blockIdx.x >> 1) * 96;

    // staging identities: lane -> row (lo: 0..63, hi: 64..95 on lanes 0..31)
    const int nlo = n0 + lane;
    const int nhi = n0 + 64 + (lane & 31);
    int blo = nlo / SPAT, rlo = nlo - blo * SPAT;
    int bhi = nhi / SPAT, rhi = nhi - bhi * SPAT;
    int ohlo = rlo / 54, owlo = rlo - ohlo * 54;
    int ohhi = rhi / 54, owhi = rhi - ohhi * 54;
    const size_t pb_lo = (size_t)blo * CIMG + ohlo * HIN + owlo;   // pixel idx
    const size_t pb_hi = (size_t)bhi * CIMG + ohhi * HIN + owhi;
    const size_t sb_lo = ((size_t)blo * IMG + ohlo * HIN + owlo) * 64;
    const size_t sb_hi = ((size_t)bhi * IMG + ohhi * HIN + owhi) * 64;

    floatx4 acc[2][2] = {};

    auto stage = [&](int ch, int buf) {
        int s = half * 81 + ch * 3 + (wave >> 2);
        int g = s * 4 + (wave & 3);          // e-group (k/8), wave-uniform
        const char *src_lo, *src_hi;
        if (g < 576) {
            int c  = g / 9;
            int rs = g - 9 * c;
            int rr = rs / 3;
            int off = c * IMG + rr * HIN + (rs - rr * 3);
            src_lo = (const char*)(act8 + (pb_lo + off) * 8);
            src_hi = (const char*)(act8 + (pb_hi + off) * 8);
        } else {
            int eb = g - 576;
            int rs = eb >> 3;
            int rr = rs / 3;
            int off = (rr * HIN + (rs - rr * 3)) * 64 + (eb & 7) * 8;
            src_lo = (const char*)(silu_t + sb_lo + off);
            src_hi = (const char*)(silu_t + sb_hi + off);
        }
        char* dst = &As[buf][wave * 96 * 16];
        GL2LDS(src_lo, dst);
        if (lane < 32) GL2LDS(src_hi, dst + 64 * 16);
    };

    stage(0, 0);
    __syncthreads();

    for (int ch = 0; ch < NCH; ++ch) {
        const int buf = ch & 1;
        if (ch + 1 < NCH) stage(ch + 1, buf ^ 1);   // async, overlaps MFMA

        const int s0 = half * 81 + ch * 3;
#pragma unroll
        for (int ks = 0; ks < 3; ++ks) {
            int gq = (s0 + ks) * 4 + quad;
            bf16x8 wfr[2], afr[2];
#pragma unroll
            for (int nt = 0; nt < 2; ++nt)
                wfr[nt] = *(const bf16x8*)(W2 +
                    ((size_t)gq * 128 + coutg * 32 + nt * 16 + l16) * 8);
#pragma unroll
            for (int mt = 0; mt < 2; ++mt)
                afr[mt] = *(const bf16x8*)(&As[buf][
                    ((ks * 4 + quad) * 96 + rowg * 32 + mt * 16 + l16) * 16]);
#pragma unroll
            for (int mt = 0; mt < 2; ++mt)
#pragma unroll
                for (int nt = 0; nt < 2; ++nt)
                    acc[mt][nt] = __builtin_amdgcn_mfma_f32_16x16x32_bf16(
                        wfr[nt], afr[mt], acc[mt][nt], 0, 0, 0);
        }
        __syncthreads();
    }

    // epilogue: D col(l16) = row n, D row(quad*4+r) = cout
#pragma unroll
    for (int mt = 0; mt < 2; ++mt) {
        int nn   = n0 + rowg * 32 + mt * 16 + l16;
        int b2   = nn / SPAT;
        int rem2 = nn - b2 * SPAT;
#pragma unroll
        for (int nt = 0; nt < 2; ++nt) {
#pragma unroll
            for (int r = 0; r < 4; ++r) {
                int o = coutg * 32 + nt * 16 + quad * 4 + r;
                size_t idx = (size_t)(b2 * 128 + o) * SPAT + rem2;
                if (MODE == 0) part[(size_t)half * NOUT + idx] = acc[mt][nt][r];
                else           atomicAdd(&outp[idx], acc[mt][nt][r]);
            }
        }
    }
}

__global__ __launch_bounds__(256) void reduce_kernel(
    const char* __restrict__ ws, float* __restrict__ outp)
{
    const floatx4* p0 = (const floatx4*)(ws + PART_OFF);
    const floatx4* p1 = p0 + NOUT / 4;
    int i = blockIdx.x * 256 + threadIdx.x;   // grid covers NOUT/4 exactly
    floatx4 a = p0[i], b = p1[i];
    ((floatx4*)outp)[i] = (floatx4){a[0] + b[0], a[1] + b[1],
                                    a[2] + b[2], a[3] + b[3]};
}

__global__ __launch_bounds__(256) void zero_kernel(float* __restrict__ outp)
{
    int i = blockIdx.x * 256 + threadIdx.x;
    ((floatx4*)outp)[i] = (floatx4){0.f, 0.f, 0.f, 0.f};
}

extern "C" void kernel_launch(void* const* d_in, const int* in_sizes, int n_in,
                              void* d_out, int out_size, void* d_ws, size_t ws_size,
                              hipStream_t stream) {
    const float* x  = (const float*)d_in[0];
    const float* bw = (const float*)d_in[1];
    const float* sw = (const float*)d_in[2];
    const float* sc = (const float*)d_in[3];
    float* out = (float*)d_out;
    char*  ws  = (char*)d_ws;

    prep_kernel<<<R_ACT_END / 256, 256, 0, stream>>>(x, bw, sw, sc, ws);

    if (ws_size >= WS_NEED) {
        kan_gemm<0><<<486, 768, 0, stream>>>(ws, out);
        reduce_kernel<<<NOUT / 4 / 256, 256, 0, stream>>>(ws, out);
    } else {
        zero_kernel<<<NOUT / 4 / 256, 256, 0, stream>>>(out);
        kan_gemm<1><<<486, 768, 0, stream>>>(ws, out);
    }
}